// Round 1
// baseline (402.844 us; speedup 1.0000x reference)
//
#include <hip/hip_runtime.h>
#include <math.h>

// Problem constants
#define NN   20000          // nodes
#define EE   320000         // edges
#define HH   128            // hidden
#define DIN  304            // 28 edge_attr+rbf cols are 0..47, hi 48..175, hj 176..303
#define DINP 320            // padded K for GEMM1
#define FSTR 328            // feat LDS row stride (u16) : 656B, 16B aligned, 2-way banks
#define MSTR 136            // h1/mij LDS row stride     : 272B, 16B aligned
#define ASTR 264            // node A LDS row stride     : 528B, 16B aligned
#define BSTR 40             // B chunk LDS row stride    : 80B, 16B aligned

typedef __attribute__((ext_vector_type(8))) short          bf16x8;
typedef __attribute__((ext_vector_type(4))) float          f32x4;
typedef __attribute__((ext_vector_type(8))) unsigned short u16x8;
typedef __attribute__((ext_vector_type(4))) unsigned short u16x4;
typedef unsigned short u16;

// fp32 -> bf16 round-to-nearest-even
__device__ __forceinline__ u16 f2b(float f) {
  union { float f; unsigned int u; } v; v.f = f;
  return (u16)((v.u + 0x7fffu + ((v.u >> 16) & 1u)) >> 16);
}

// Stage one [128 x 32] bf16 B-chunk (pre-packed contiguous) into LDS.
// src layout: idx*8 contiguous u16; dst: [n][BSTR].
__device__ __forceinline__ void stage_chunk(const u16* __restrict__ src, u16* dst, int t) {
  #pragma unroll
  for (int p = 0; p < 2; ++p) {
    int idx = p * 256 + t;          // 0..511 chunks of 8 u16
    int n = idx >> 2, j = idx & 3;
    *(u16x8*)&dst[n * BSTR + j * 8] = *(const u16x8*)&src[idx * 8];
  }
}

// ---------------------------------------------------------------------------
// prep: convert weights to bf16, transposed + K-chunk-packed: out[kc][n][kk]
// = W[k=kc*32+kk][n]   (zero pad k >= K)
// sizes (u16): ew1c 40960, ew2c 16384, xw1c 16384, nw1c 32768, nw2c 16384
// ---------------------------------------------------------------------------
__global__ void prep_kernel(const float* __restrict__ ew1, const float* __restrict__ ew2,
                            const float* __restrict__ xw1, const float* __restrict__ nw1,
                            const float* __restrict__ nw2,
                            u16* __restrict__ ew1c, u16* __restrict__ ew2c,
                            u16* __restrict__ xw1c, u16* __restrict__ nw1c,
                            u16* __restrict__ nw2c) {
  int idx = blockIdx.x * 256 + threadIdx.x;
  if (idx < 40960) {
    int kc = idx >> 12, rem = idx & 4095, n = rem >> 5, kk = rem & 31;
    int k = kc * 32 + kk;
    ew1c[idx] = (k < DIN) ? f2b(ew1[k * HH + n]) : (u16)0;
  } else if (idx < 40960 + 16384) {
    int i2 = idx - 40960;
    int kc = i2 >> 12, rem = i2 & 4095, n = rem >> 5, kk = rem & 31;
    ew2c[i2] = f2b(ew2[(kc * 32 + kk) * HH + n]);
  } else if (idx < 40960 + 32768) {
    int i2 = idx - (40960 + 16384);
    int kc = i2 >> 12, rem = i2 & 4095, n = rem >> 5, kk = rem & 31;
    xw1c[i2] = f2b(xw1[(kc * 32 + kk) * HH + n]);
  } else if (idx < 40960 + 32768 + 32768) {
    int i2 = idx - (40960 + 32768);
    int kc = i2 >> 12, rem = i2 & 4095, n = rem >> 5, kk = rem & 31;
    nw1c[i2] = f2b(nw1[(kc * 32 + kk) * HH + n]);   // K=256
  } else if (idx < 122880) {
    int i2 = idx - (40960 + 32768 + 32768);
    int kc = i2 >> 12, rem = i2 & 4095, n = rem >> 5, kk = rem & 31;
    nw2c[i2] = f2b(nw2[(kc * 32 + kk) * HH + n]);
  }
}

// ---------------------------------------------------------------------------
// edge kernel: 64 edges per block, 256 threads (4 waves x 16 rows).
// feat -> GEMM1(ew1,relu) -> GEMM2(ew2,relu)=mij -> eij -> mi atomics
//      -> GEMM3(xw1,relu) -> xg -> dx atomics
// ---------------------------------------------------------------------------
__global__ __launch_bounds__(256, 2) void edge_kernel(
    const float* __restrict__ h, const float* __restrict__ x,
    const float* __restrict__ edge_attr,
    const u16* __restrict__ ew1c, const float* __restrict__ eb1,
    const u16* __restrict__ ew2c, const float* __restrict__ eb2,
    const float* __restrict__ inf_w, const float* __restrict__ inf_b,
    const u16* __restrict__ xw1c, const float* __restrict__ xb1,
    const float* __restrict__ xw2, const float* __restrict__ xb2,
    const int* __restrict__ edge_index,
    float* __restrict__ mi, float* __restrict__ dx) {
  __shared__ u16 feat_s[64 * FSTR];   // later reused (stride MSTR) for mij
  __shared__ u16 h1_s[64 * MSTR];
  __shared__ u16 B_s[128 * BSTR];
  __shared__ float relx_s[64][4];
  __shared__ int dst_s[64];
  __shared__ int src_s[64];

  const int t  = threadIdx.x;
  const int w  = t >> 6;        // wave 0..3, owns rows w*16..w*16+15
  const int l  = t & 63;
  const int l15 = l & 15;
  const int q  = l >> 4;        // quad 0..3
  const int e0 = blockIdx.x * 64;

  // ---- phase A: indices + rel_x + |rel_x| ----
  if (t < 64) {
    int d = edge_index[e0 + t];
    int s = edge_index[EE + e0 + t];
    dst_s[t] = d; src_s[t] = s;
    float rx = x[d * 3 + 0] - x[s * 3 + 0];
    float ry = x[d * 3 + 1] - x[s * 3 + 1];
    float rz = x[d * 3 + 2] - x[s * 3 + 2];
    relx_s[t][0] = rx; relx_s[t][1] = ry; relx_s[t][2] = rz;
    relx_s[t][3] = sqrtf(rx * rx + ry * ry + rz * rz);
  }
  __syncthreads();

  // ---- phase B: build feat tile (bf16) ----
  const float step  = 100.0f / 19.0f;             // linspace(0,100,20) spacing
  const float coeff = -0.5f / (step * step);
  for (int idx = t; idx < 64 * 64; idx += 256) {  // cols 0..47 + zero pad 304..319
    int e = idx >> 6, c = idx & 63;
    float v;
    if (c < 28)       v = edge_attr[(size_t)(e0 + e) * 28 + c];
    else if (c < 48) { float d = relx_s[e][3] - (float)(c - 28) * step; v = __expf(coeff * d * d); }
    else              v = 0.0f;
    int col = (c < 48) ? c : (256 + c);           // 48..63 -> 304..319
    feat_s[e * FSTR + col] = f2b(v);
  }
  #pragma unroll 1
  for (int pass = 0; pass < 8; ++pass) {          // hi (48..175) and hj (176..303)
    int e  = pass * 8 + (t >> 5);
    int c4 = (t & 31) * 4;
    float4 hv = *(const float4*)&h[(size_t)dst_s[e] * HH + c4];
    u16x4 a; a.x = f2b(hv.x); a.y = f2b(hv.y); a.z = f2b(hv.z); a.w = f2b(hv.w);
    *(u16x4*)&feat_s[e * FSTR + 48 + c4] = a;
    float4 gv = *(const float4*)&h[(size_t)src_s[e] * HH + c4];
    u16x4 b; b.x = f2b(gv.x); b.y = f2b(gv.y); b.z = f2b(gv.z); b.w = f2b(gv.w);
    *(u16x4*)&feat_s[e * FSTR + 176 + c4] = b;
  }
  __syncthreads();

  // ---- GEMM1: feat[64x320] @ ew1 -> h1 (relu) ----
  f32x4 acc[8];
  #pragma unroll
  for (int nt = 0; nt < 8; ++nt) acc[nt] = (f32x4){0.f, 0.f, 0.f, 0.f};
  for (int kc = 0; kc < 10; ++kc) {
    __syncthreads();
    stage_chunk(ew1c + (size_t)kc * 4096, B_s, t);
    __syncthreads();
    bf16x8 a = *(const bf16x8*)&feat_s[(w * 16 + l15) * FSTR + kc * 32 + q * 8];
    #pragma unroll
    for (int nt = 0; nt < 8; ++nt) {
      bf16x8 b = *(const bf16x8*)&B_s[(nt * 16 + l15) * BSTR + q * 8];
      acc[nt] = __builtin_amdgcn_mfma_f32_16x16x32_bf16(a, b, acc[nt], 0, 0, 0);
    }
  }
  #pragma unroll
  for (int nt = 0; nt < 8; ++nt) {
    float b1 = eb1[nt * 16 + l15];
    #pragma unroll
    for (int r = 0; r < 4; ++r) {
      float v = acc[nt][r] + b1; v = v > 0.f ? v : 0.f;
      h1_s[(w * 16 + q * 4 + r) * MSTR + nt * 16 + l15] = f2b(v);
    }
  }

  // ---- GEMM2: h1[64x128] @ ew2 -> mij (relu) ----
  #pragma unroll
  for (int nt = 0; nt < 8; ++nt) acc[nt] = (f32x4){0.f, 0.f, 0.f, 0.f};
  for (int kc = 0; kc < 4; ++kc) {
    __syncthreads();
    stage_chunk(ew2c + (size_t)kc * 4096, B_s, t);
    __syncthreads();
    bf16x8 a = *(const bf16x8*)&h1_s[(w * 16 + l15) * MSTR + kc * 32 + q * 8];
    #pragma unroll
    for (int nt = 0; nt < 8; ++nt) {
      bf16x8 b = *(const bf16x8*)&B_s[(nt * 16 + l15) * BSTR + q * 8];
      acc[nt] = __builtin_amdgcn_mfma_f32_16x16x32_bf16(a, b, acc[nt], 0, 0, 0);
    }
  }
  float mijv[8][4];
  #pragma unroll
  for (int nt = 0; nt < 8; ++nt) {
    float b2 = eb2[nt * 16 + l15];
    #pragma unroll
    for (int r = 0; r < 4; ++r) {
      float v = acc[nt][r] + b2; v = v > 0.f ? v : 0.f;
      mijv[nt][r] = v;
      feat_s[(w * 16 + q * 4 + r) * MSTR + nt * 16 + l15] = f2b(v);  // mij tile (reuse feat_s)
    }
  }

  // ---- eij = sigmoid(mij @ inf_w + inf_b); mi += mij*eij (atomics) ----
  float iw[8];
  #pragma unroll
  for (int nt = 0; nt < 8; ++nt) iw[nt] = inf_w[nt * 16 + l15];
  float ib = inf_b[0];
  #pragma unroll
  for (int r = 0; r < 4; ++r) {
    float p = 0.f;
    #pragma unroll
    for (int nt = 0; nt < 8; ++nt) p += mijv[nt][r] * iw[nt];
    p += __shfl_xor(p, 1, 16);
    p += __shfl_xor(p, 2, 16);
    p += __shfl_xor(p, 4, 16);
    p += __shfl_xor(p, 8, 16);
    float eij = 1.0f / (1.0f + __expf(-(p + ib)));
    int row = w * 16 + q * 4 + r;
    int d = dst_s[row];
    #pragma unroll
    for (int nt = 0; nt < 8; ++nt)
      atomicAdd(&mi[(size_t)d * HH + nt * 16 + l15], mijv[nt][r] * eij);
  }

  // ---- GEMM3: mij[64x128] @ xw1 -> h3 (relu); xg = h3 @ xw2 + xb2; dx atomics ----
  #pragma unroll
  for (int nt = 0; nt < 8; ++nt) acc[nt] = (f32x4){0.f, 0.f, 0.f, 0.f};
  for (int kc = 0; kc < 4; ++kc) {
    __syncthreads();
    stage_chunk(xw1c + (size_t)kc * 4096, B_s, t);
    __syncthreads();
    bf16x8 a = *(const bf16x8*)&feat_s[(w * 16 + l15) * MSTR + kc * 32 + q * 8];
    #pragma unroll
    for (int nt = 0; nt < 8; ++nt) {
      bf16x8 b = *(const bf16x8*)&B_s[(nt * 16 + l15) * BSTR + q * 8];
      acc[nt] = __builtin_amdgcn_mfma_f32_16x16x32_bf16(a, b, acc[nt], 0, 0, 0);
    }
  }
  float xv[8], b3[8];
  #pragma unroll
  for (int nt = 0; nt < 8; ++nt) { xv[nt] = xw2[nt * 16 + l15]; b3[nt] = xb1[nt * 16 + l15]; }
  float xb2_0 = xb2[0];
  #pragma unroll
  for (int r = 0; r < 4; ++r) {
    float p = 0.f;
    #pragma unroll
    for (int nt = 0; nt < 8; ++nt) {
      float v = acc[nt][r] + b3[nt]; v = v > 0.f ? v : 0.f;
      p += v * xv[nt];
    }
    p += __shfl_xor(p, 1, 16);
    p += __shfl_xor(p, 2, 16);
    p += __shfl_xor(p, 4, 16);
    p += __shfl_xor(p, 8, 16);
    float xg = p + xb2_0;
    int row = w * 16 + q * 4 + r;
    int d = dst_s[row];
    if (l15 < 3) atomicAdd(&dx[(size_t)d * 3 + l15], relx_s[row][l15] * xg);
  }
}

// ---------------------------------------------------------------------------
// node kernel: out = relu([mi,h]@nw1+nb1)@nw2+nb2 ; x_out = x + dx/E
// 64 rows per block, 256 threads.
// ---------------------------------------------------------------------------
__global__ __launch_bounds__(256, 2) void node_kernel(
    const float* __restrict__ h, const float* __restrict__ x,
    const u16* __restrict__ nw1c, const float* __restrict__ nb1,
    const u16* __restrict__ nw2c, const float* __restrict__ nb2,
    const float* __restrict__ mi, const float* __restrict__ dx,
    float* __restrict__ out) {
  __shared__ u16 A_s[64 * ASTR];
  __shared__ u16 h1_s[64 * MSTR];
  __shared__ u16 B_s[128 * BSTR];

  const int t = threadIdx.x;
  const int w = t >> 6;
  const int l = t & 63;
  const int l15 = l & 15;
  const int q = l >> 4;
  const int r0 = blockIdx.x * 64;

  // build A = [mi | h] in bf16
  #pragma unroll 1
  for (int pass = 0; pass < 8; ++pass) {
    int e = pass * 8 + (t >> 5);
    int grow = r0 + e;
    int c4 = (t & 31) * 4;
    float4 mv = {0.f, 0.f, 0.f, 0.f}, hv = {0.f, 0.f, 0.f, 0.f};
    if (grow < NN) {
      mv = *(const float4*)&mi[(size_t)grow * HH + c4];
      hv = *(const float4*)&h[(size_t)grow * HH + c4];
    }
    u16x4 a; a.x = f2b(mv.x); a.y = f2b(mv.y); a.z = f2b(mv.z); a.w = f2b(mv.w);
    *(u16x4*)&A_s[e * ASTR + c4] = a;
    u16x4 b; b.x = f2b(hv.x); b.y = f2b(hv.y); b.z = f2b(hv.z); b.w = f2b(hv.w);
    *(u16x4*)&A_s[e * ASTR + 128 + c4] = b;
  }
  __syncthreads();

  f32x4 acc[8];
  #pragma unroll
  for (int nt = 0; nt < 8; ++nt) acc[nt] = (f32x4){0.f, 0.f, 0.f, 0.f};
  for (int kc = 0; kc < 8; ++kc) {   // K = 256
    __syncthreads();
    stage_chunk(nw1c + (size_t)kc * 4096, B_s, t);
    __syncthreads();
    bf16x8 a = *(const bf16x8*)&A_s[(w * 16 + l15) * ASTR + kc * 32 + q * 8];
    #pragma unroll
    for (int nt = 0; nt < 8; ++nt) {
      bf16x8 b = *(const bf16x8*)&B_s[(nt * 16 + l15) * BSTR + q * 8];
      acc[nt] = __builtin_amdgcn_mfma_f32_16x16x32_bf16(a, b, acc[nt], 0, 0, 0);
    }
  }
  #pragma unroll
  for (int nt = 0; nt < 8; ++nt) {
    float b1 = nb1[nt * 16 + l15];
    #pragma unroll
    for (int r = 0; r < 4; ++r) {
      float v = acc[nt][r] + b1; v = v > 0.f ? v : 0.f;
      h1_s[(w * 16 + q * 4 + r) * MSTR + nt * 16 + l15] = f2b(v);
    }
  }
  #pragma unroll
  for (int nt = 0; nt < 8; ++nt) acc[nt] = (f32x4){0.f, 0.f, 0.f, 0.f};
  for (int kc = 0; kc < 4; ++kc) {   // K = 128
    __syncthreads();
    stage_chunk(nw2c + (size_t)kc * 4096, B_s, t);
    __syncthreads();
    bf16x8 a = *(const bf16x8*)&h1_s[(w * 16 + l15) * MSTR + kc * 32 + q * 8];
    #pragma unroll
    for (int nt = 0; nt < 8; ++nt) {
      bf16x8 b = *(const bf16x8*)&B_s[(nt * 16 + l15) * BSTR + q * 8];
      acc[nt] = __builtin_amdgcn_mfma_f32_16x16x32_bf16(a, b, acc[nt], 0, 0, 0);
    }
  }
  #pragma unroll
  for (int nt = 0; nt < 8; ++nt) {
    float b2 = nb2[nt * 16 + l15];
    #pragma unroll
    for (int r = 0; r < 4; ++r) {
      int grow = r0 + w * 16 + q * 4 + r;
      if (grow < NN) out[(size_t)grow * HH + nt * 16 + l15] = acc[nt][r] + b2;
    }
  }
  // x output
  if (t < 192) {
    int rr = t / 3, dim = t % 3;
    int grow = r0 + rr;
    if (grow < NN)
      out[(size_t)NN * HH + (size_t)grow * 3 + dim] =
          x[(size_t)grow * 3 + dim] + dx[(size_t)grow * 3 + dim] * (1.0f / (float)EE);
  }
}

// ---------------------------------------------------------------------------
// launch
// ---------------------------------------------------------------------------
extern "C" void kernel_launch(void* const* d_in, const int* in_sizes, int n_in,
                              void* d_out, int out_size, void* d_ws, size_t ws_size,
                              hipStream_t stream) {
  const float* h         = (const float*)d_in[0];
  const float* x         = (const float*)d_in[1];
  const float* edge_attr = (const float*)d_in[2];
  const float* ew1 = (const float*)d_in[3];
  const float* eb1 = (const float*)d_in[4];
  const float* ew2 = (const float*)d_in[5];
  const float* eb2 = (const float*)d_in[6];
  const float* inf_w = (const float*)d_in[7];
  const float* inf_b = (const float*)d_in[8];
  const float* nw1 = (const float*)d_in[9];
  const float* nb1 = (const float*)d_in[10];
  const float* nw2 = (const float*)d_in[11];
  const float* nb2 = (const float*)d_in[12];
  const float* xw1 = (const float*)d_in[13];
  const float* xb1 = (const float*)d_in[14];
  const float* xw2 = (const float*)d_in[15];
  const float* xb2 = (const float*)d_in[16];
  const int* edge_index = (const int*)d_in[17];
  float* out = (float*)d_out;

  char* wsb = (char*)d_ws;
  u16* ew1c = (u16*)(wsb + 0);          //  81920 B
  u16* ew2c = (u16*)(wsb + 81920);      //  32768 B
  u16* xw1c = (u16*)(wsb + 114688);     //  32768 B
  u16* nw1c = (u16*)(wsb + 147456);     //  65536 B
  u16* nw2c = (u16*)(wsb + 212992);     //  32768 B
  float* mi = (float*)(wsb + 245760);   // 10240000 B
  float* dx = (float*)(wsb + 10485760); //   240000 B

  // zero the accumulators (ws is poisoned before every timed launch)
  hipMemsetAsync(wsb + 245760, 0, 10240000 + 240000, stream);

  prep_kernel<<<(122880 + 255) / 256, 256, 0, stream>>>(
      ew1, ew2, xw1, nw1, nw2, ew1c, ew2c, xw1c, nw1c, nw2c);

  edge_kernel<<<EE / 64, 256, 0, stream>>>(
      h, x, edge_attr, ew1c, eb1, ew2c, eb2, inf_w, inf_b,
      xw1c, xb1, xw2, xb2, edge_index, mi, dx);

  node_kernel<<<(NN + 63) / 64, 256, 0, stream>>>(
      h, x, nw1c, nb1, nw2c, nb2, mi, dx, out);
}

// Round 2
// 335.741 us; speedup vs baseline: 1.1999x; 1.1999x over previous
//
#include <hip/hip_runtime.h>
#include <math.h>

// Problem constants
#define NN   20000          // nodes
#define EE   320000         // edges
#define HH   128            // hidden
#define MSTR 136            // h1/mij LDS row stride (u16): 272B = 17*16B (odd -> conflict-light)
#define ARSTR 72            // attr+rbf LDS row stride (u16): 144B = 9*16B

typedef __attribute__((ext_vector_type(8))) short          bf16x8;
typedef __attribute__((ext_vector_type(4))) float          f32x4;
typedef unsigned short u16;

// fp32 -> bf16 round-to-nearest-even
__device__ __forceinline__ u16 f2b(float f) {
  union { float f; unsigned int u; } v; v.f = f;
  return (u16)((v.u + 0x7fffu + ((v.u >> 16) & 1u)) >> 16);
}

__device__ __forceinline__ bf16x8 cvt8(float4 a, float4 b) {
  bf16x8 r;
  r[0] = (short)f2b(a.x); r[1] = (short)f2b(a.y);
  r[2] = (short)f2b(a.z); r[3] = (short)f2b(a.w);
  r[4] = (short)f2b(b.x); r[5] = (short)f2b(b.y);
  r[6] = (short)f2b(b.z); r[7] = (short)f2b(b.w);
  return r;
}

// ---------------------------------------------------------------------------
// prep: bf16 weights packed for per-wave coalesced fragment loads:
//   pack[kc][nt][l][j]  (j=0..7 contiguous)  l = q*16 + l15
//   value = W[k = kc*32 + (l>>4)*8 + j][n = nt*16 + (l&15)]
// Lane l loads pack + kc*4096 + nt*512 + l*8  -> 16B/lane, fully coalesced.
// ew1 additionally has its K rows permuted to the new feat order
// (hi | hj | attr | rbf | pad):  k_orig = k<256 ? k+48 : (k<304 ? k-256 : pad)
// sizes (u16): ew1c 40960, ew2c 16384, xw1c 16384, nw1c 32768, nw2c 16384
// ---------------------------------------------------------------------------
__global__ void prep_kernel(const float* __restrict__ ew1, const float* __restrict__ ew2,
                            const float* __restrict__ xw1, const float* __restrict__ nw1,
                            const float* __restrict__ nw2,
                            u16* __restrict__ ew1c, u16* __restrict__ ew2c,
                            u16* __restrict__ xw1c, u16* __restrict__ nw1c,
                            u16* __restrict__ nw2c) {
  int idx = blockIdx.x * 256 + threadIdx.x;
  int i2, n, k;
  u16* dst;
  const float* src;
  if (idx < 40960)              { i2 = idx;          dst = ew1c; src = ew1; }
  else if (idx < 57344)         { i2 = idx - 40960;  dst = ew2c; src = ew2; }
  else if (idx < 73728)         { i2 = idx - 57344;  dst = xw1c; src = xw1; }
  else if (idx < 106496)        { i2 = idx - 73728;  dst = nw1c; src = nw1; }
  else if (idx < 122880)        { i2 = idx - 106496; dst = nw2c; src = nw2; }
  else return;
  {
    int kc = i2 >> 12, rem = i2 & 4095, nt = rem >> 9, rem2 = rem & 511;
    int l = rem2 >> 3, j = rem2 & 7;
    n = nt * 16 + (l & 15);
    k = kc * 32 + (l >> 4) * 8 + j;
  }
  float v;
  if (dst == ew1c) {
    if (k < 256)      v = src[(k + 48) * HH + n];   // hi | hj block
    else if (k < 304) v = src[(k - 256) * HH + n];  // attr | rbf block
    else              v = 0.0f;                     // pad
  } else {
    v = src[k * HH + n];                            // K is exact for the rest
  }
  dst[i2] = f2b(v);
}

// ---------------------------------------------------------------------------
// edge kernel: 64 edges/block, 256 threads (4 waves x 16 rows).
// feat (reordered: hi|hj|attr|rbf) -> GEMM1(relu) -> GEMM2(relu)=mij
//   -> eij -> mi atomics -> GEMM3(relu) -> xg -> dx atomics
// A for hi/hj chunks loads DIRECTLY from h (global); attr+rbf via small LDS.
// B fragments load directly from packed global (L2-hot) -> no inner barriers.
// ---------------------------------------------------------------------------
__global__ __launch_bounds__(256, 4) void edge_kernel(
    const float* __restrict__ h, const float* __restrict__ x,
    const float* __restrict__ edge_attr,
    const u16* __restrict__ ew1c, const float* __restrict__ eb1,
    const u16* __restrict__ ew2c, const float* __restrict__ eb2,
    const float* __restrict__ inf_w, const float* __restrict__ inf_b,
    const u16* __restrict__ xw1c, const float* __restrict__ xb1,
    const float* __restrict__ xw2, const float* __restrict__ xb2,
    const int* __restrict__ edge_index,
    float* __restrict__ mi, float* __restrict__ dx) {
  __shared__ u16 ar_s[64 * ARSTR];    // attr(28)+rbf(20)+pad cols 0..63 of feat tail
  __shared__ u16 h1_s[64 * MSTR];     // GEMM1 out; later overlaid with mij
  __shared__ float relx_s[64][4];
  __shared__ int dst_s[64];
  __shared__ int src_s[64];

  const int t   = threadIdx.x;
  const int w   = t >> 6;
  const int l   = t & 63;
  const int l15 = l & 15;
  const int q   = l >> 4;
  const int e0  = blockIdx.x * 64;
  const int myrow = w * 16 + l15;

  // ---- phase A: indices + rel_x + |rel_x| ----
  if (t < 64) {
    int d = edge_index[e0 + t];
    int s = edge_index[EE + e0 + t];
    dst_s[t] = d; src_s[t] = s;
    float rx = x[d * 3 + 0] - x[s * 3 + 0];
    float ry = x[d * 3 + 1] - x[s * 3 + 1];
    float rz = x[d * 3 + 2] - x[s * 3 + 2];
    relx_s[t][0] = rx; relx_s[t][1] = ry; relx_s[t][2] = rz;
    relx_s[t][3] = sqrtf(rx * rx + ry * ry + rz * rz);
  }
  __syncthreads();

  // ---- issue hi/hj gathers for this wave's rows (overlap with ar build) ----
  const int dstv = dst_s[myrow];
  const int srcv = src_s[myrow];
  const float* hd = h + (size_t)dstv * HH;
  const float* hs = h + (size_t)srcv * HH;
  float4 t0[8], t1[8];
  #pragma unroll
  for (int c = 0; c < 4; ++c) {
    t0[c]     = *(const float4*)&hd[c * 32 + q * 8];
    t1[c]     = *(const float4*)&hd[c * 32 + q * 8 + 4];
    t0[4 + c] = *(const float4*)&hs[c * 32 + q * 8];
    t1[4 + c] = *(const float4*)&hs[c * 32 + q * 8 + 4];
  }

  // ---- attr + rbf tile (feat cols 256..319 in new order) ----
  const float step  = 100.0f / 19.0f;
  const float coeff = -0.5f / (step * step);
  for (int idx = t; idx < 64 * 64; idx += 256) {
    int e = idx >> 6, c = idx & 63;
    float v = 0.0f;
    if (c < 28)      v = edge_attr[(size_t)(e0 + e) * 28 + c];
    else if (c < 48) { float d = relx_s[e][3] - (float)(c - 28) * step; v = __expf(coeff * d * d); }
    ar_s[e * ARSTR + c] = f2b(v);
  }
  __syncthreads();

  // ---- A fragments for GEMM1 (K = 320: 4 hi + 4 hj + 2 attr/rbf chunks) ----
  bf16x8 afrag[10];
  #pragma unroll
  for (int c = 0; c < 8; ++c) afrag[c] = cvt8(t0[c], t1[c]);
  afrag[8] = *(const bf16x8*)&ar_s[myrow * ARSTR + q * 8];
  afrag[9] = *(const bf16x8*)&ar_s[myrow * ARSTR + 32 + q * 8];

  // ---- GEMM1: no barriers, B straight from global (packed, coalesced) ----
  f32x4 acc[8];
  #pragma unroll
  for (int nt = 0; nt < 8; ++nt) acc[nt] = (f32x4){0.f, 0.f, 0.f, 0.f};
  #pragma unroll
  for (int kc = 0; kc < 10; ++kc) {
    const u16* bp = ew1c + (kc << 12) + l * 8;
    #pragma unroll
    for (int nt = 0; nt < 8; ++nt) {
      bf16x8 b = *(const bf16x8*)(bp + nt * 512);
      acc[nt] = __builtin_amdgcn_mfma_f32_16x16x32_bf16(afrag[kc], b, acc[nt], 0, 0, 0);
    }
  }
  #pragma unroll
  for (int nt = 0; nt < 8; ++nt) {
    float b1 = eb1[nt * 16 + l15];
    #pragma unroll
    for (int r = 0; r < 4; ++r) {
      float v = acc[nt][r] + b1; v = v > 0.f ? v : 0.f;
      h1_s[(w * 16 + q * 4 + r) * MSTR + nt * 16 + l15] = f2b(v);
    }
  }
  __syncthreads();

  // ---- GEMM2: A from h1_s, B from ew2c global ----
  bf16x8 a2[4];
  #pragma unroll
  for (int kc = 0; kc < 4; ++kc)
    a2[kc] = *(const bf16x8*)&h1_s[myrow * MSTR + kc * 32 + q * 8];
  #pragma unroll
  for (int nt = 0; nt < 8; ++nt) acc[nt] = (f32x4){0.f, 0.f, 0.f, 0.f};
  #pragma unroll
  for (int kc = 0; kc < 4; ++kc) {
    const u16* bp = ew2c + (kc << 12) + l * 8;
    #pragma unroll
    for (int nt = 0; nt < 8; ++nt) {
      bf16x8 b = *(const bf16x8*)(bp + nt * 512);
      acc[nt] = __builtin_amdgcn_mfma_f32_16x16x32_bf16(a2[kc], b, acc[nt], 0, 0, 0);
    }
  }
  float mijv[8][4];
  #pragma unroll
  for (int nt = 0; nt < 8; ++nt) {
    float b2 = eb2[nt * 16 + l15];
    #pragma unroll
    for (int r = 0; r < 4; ++r) {
      float v = acc[nt][r] + b2;
      mijv[nt][r] = v > 0.f ? v : 0.f;
    }
  }
  __syncthreads();                      // all h1_s reads done -> safe to overlay mij
  #pragma unroll
  for (int nt = 0; nt < 8; ++nt)
    #pragma unroll
    for (int r = 0; r < 4; ++r)
      h1_s[(w * 16 + q * 4 + r) * MSTR + nt * 16 + l15] = f2b(mijv[nt][r]);

  // ---- eij = sigmoid(mij @ inf_w + b); mi += mij*eij (atomics) ----
  float iw[8];
  #pragma unroll
  for (int nt = 0; nt < 8; ++nt) iw[nt] = inf_w[nt * 16 + l15];
  float ib = inf_b[0];
  #pragma unroll
  for (int r = 0; r < 4; ++r) {
    float p = 0.f;
    #pragma unroll
    for (int nt = 0; nt < 8; ++nt) p += mijv[nt][r] * iw[nt];
    p += __shfl_xor(p, 1, 16);
    p += __shfl_xor(p, 2, 16);
    p += __shfl_xor(p, 4, 16);
    p += __shfl_xor(p, 8, 16);
    float eij = 1.0f / (1.0f + __expf(-(p + ib)));
    int d = dst_s[w * 16 + q * 4 + r];
    #pragma unroll
    for (int nt = 0; nt < 8; ++nt)
      atomicAdd(&mi[(size_t)d * HH + nt * 16 + l15], mijv[nt][r] * eij);
  }
  __syncthreads();                      // mij tile fully written

  // ---- GEMM3: A = mij (LDS), B = xw1c; then xg row-reduce; dx atomics ----
  bf16x8 a3[4];
  #pragma unroll
  for (int kc = 0; kc < 4; ++kc)
    a3[kc] = *(const bf16x8*)&h1_s[myrow * MSTR + kc * 32 + q * 8];
  #pragma unroll
  for (int nt = 0; nt < 8; ++nt) acc[nt] = (f32x4){0.f, 0.f, 0.f, 0.f};
  #pragma unroll
  for (int kc = 0; kc < 4; ++kc) {
    const u16* bp = xw1c + (kc << 12) + l * 8;
    #pragma unroll
    for (int nt = 0; nt < 8; ++nt) {
      bf16x8 b = *(const bf16x8*)(bp + nt * 512);
      acc[nt] = __builtin_amdgcn_mfma_f32_16x16x32_bf16(a3[kc], b, acc[nt], 0, 0, 0);
    }
  }
  float xv[8], b3[8];
  #pragma unroll
  for (int nt = 0; nt < 8; ++nt) { xv[nt] = xw2[nt * 16 + l15]; b3[nt] = xb1[nt * 16 + l15]; }
  float xb2_0 = xb2[0];
  #pragma unroll
  for (int r = 0; r < 4; ++r) {
    float p = 0.f;
    #pragma unroll
    for (int nt = 0; nt < 8; ++nt) {
      float v = acc[nt][r] + b3[nt]; v = v > 0.f ? v : 0.f;
      p += v * xv[nt];
    }
    p += __shfl_xor(p, 1, 16);
    p += __shfl_xor(p, 2, 16);
    p += __shfl_xor(p, 4, 16);
    p += __shfl_xor(p, 8, 16);
    float xg = p + xb2_0;
    int row = w * 16 + q * 4 + r;
    if (l15 < 3) atomicAdd(&dx[(size_t)dst_s[row] * 3 + l15], relx_s[row][l15] * xg);
  }
}

// ---------------------------------------------------------------------------
// node kernel: out = relu([mi,h]@nw1+nb1)@nw2+nb2 ; x_out = x + dx/E
// A direct from global (mi rows then h rows), B direct from packed global.
// One barrier per block.
// ---------------------------------------------------------------------------
__global__ __launch_bounds__(256, 4) void node_kernel(
    const float* __restrict__ h, const float* __restrict__ x,
    const u16* __restrict__ nw1c, const float* __restrict__ nb1,
    const u16* __restrict__ nw2c, const float* __restrict__ nb2,
    const float* __restrict__ mi, const float* __restrict__ dx,
    float* __restrict__ out) {
  __shared__ u16 h1_s[64 * MSTR];

  const int t   = threadIdx.x;
  const int w   = t >> 6;
  const int l   = t & 63;
  const int l15 = l & 15;
  const int q   = l >> 4;
  const int r0  = blockIdx.x * 64;
  const int myrow = w * 16 + l15;
  const int grow  = r0 + myrow;
  const int gr    = grow < NN ? grow : NN - 1;   // clamp loads; stores guarded

  const float* mp = mi + (size_t)gr * HH;
  const float* hp = h + (size_t)gr * HH;
  bf16x8 afrag[8];
  #pragma unroll
  for (int c = 0; c < 4; ++c) {
    float4 a0 = *(const float4*)&mp[c * 32 + q * 8];
    float4 a1 = *(const float4*)&mp[c * 32 + q * 8 + 4];
    afrag[c] = cvt8(a0, a1);
    float4 b0 = *(const float4*)&hp[c * 32 + q * 8];
    float4 b1 = *(const float4*)&hp[c * 32 + q * 8 + 4];
    afrag[4 + c] = cvt8(b0, b1);
  }

  f32x4 acc[8];
  #pragma unroll
  for (int nt = 0; nt < 8; ++nt) acc[nt] = (f32x4){0.f, 0.f, 0.f, 0.f};
  #pragma unroll
  for (int kc = 0; kc < 8; ++kc) {     // K = 256
    const u16* bp = nw1c + (kc << 12) + l * 8;
    #pragma unroll
    for (int nt = 0; nt < 8; ++nt) {
      bf16x8 b = *(const bf16x8*)(bp + nt * 512);
      acc[nt] = __builtin_amdgcn_mfma_f32_16x16x32_bf16(afrag[kc], b, acc[nt], 0, 0, 0);
    }
  }
  #pragma unroll
  for (int nt = 0; nt < 8; ++nt) {
    float b1 = nb1[nt * 16 + l15];
    #pragma unroll
    for (int r = 0; r < 4; ++r) {
      float v = acc[nt][r] + b1; v = v > 0.f ? v : 0.f;
      h1_s[(w * 16 + q * 4 + r) * MSTR + nt * 16 + l15] = f2b(v);
    }
  }
  __syncthreads();

  bf16x8 a2[4];
  #pragma unroll
  for (int kc = 0; kc < 4; ++kc)
    a2[kc] = *(const bf16x8*)&h1_s[myrow * MSTR + kc * 32 + q * 8];
  #pragma unroll
  for (int nt = 0; nt < 8; ++nt) acc[nt] = (f32x4){0.f, 0.f, 0.f, 0.f};
  #pragma unroll
  for (int kc = 0; kc < 4; ++kc) {     // K = 128
    const u16* bp = nw2c + (kc << 12) + l * 8;
    #pragma unroll
    for (int nt = 0; nt < 8; ++nt) {
      bf16x8 b = *(const bf16x8*)(bp + nt * 512);
      acc[nt] = __builtin_amdgcn_mfma_f32_16x16x32_bf16(a2[kc], b, acc[nt], 0, 0, 0);
    }
  }
  #pragma unroll
  for (int nt = 0; nt < 8; ++nt) {
    float b2 = nb2[nt * 16 + l15];
    #pragma unroll
    for (int r = 0; r < 4; ++r) {
      int gr2 = r0 + w * 16 + q * 4 + r;
      if (gr2 < NN) out[(size_t)gr2 * HH + nt * 16 + l15] = acc[nt][r] + b2;
    }
  }
  // x output
  if (t < 192) {
    int rr = t / 3, dim = t % 3;
    int gr2 = r0 + rr;
    if (gr2 < NN)
      out[(size_t)NN * HH + (size_t)gr2 * 3 + dim] =
          x[(size_t)gr2 * 3 + dim] + dx[(size_t)gr2 * 3 + dim] * (1.0f / (float)EE);
  }
}

// ---------------------------------------------------------------------------
// launch
// ---------------------------------------------------------------------------
extern "C" void kernel_launch(void* const* d_in, const int* in_sizes, int n_in,
                              void* d_out, int out_size, void* d_ws, size_t ws_size,
                              hipStream_t stream) {
  const float* h         = (const float*)d_in[0];
  const float* x         = (const float*)d_in[1];
  const float* edge_attr = (const float*)d_in[2];
  const float* ew1 = (const float*)d_in[3];
  const float* eb1 = (const float*)d_in[4];
  const float* ew2 = (const float*)d_in[5];
  const float* eb2 = (const float*)d_in[6];
  const float* inf_w = (const float*)d_in[7];
  const float* inf_b = (const float*)d_in[8];
  const float* nw1 = (const float*)d_in[9];
  const float* nb1 = (const float*)d_in[10];
  const float* nw2 = (const float*)d_in[11];
  const float* nb2 = (const float*)d_in[12];
  const float* xw1 = (const float*)d_in[13];
  const float* xb1 = (const float*)d_in[14];
  const float* xw2 = (const float*)d_in[15];
  const float* xb2 = (const float*)d_in[16];
  const int* edge_index = (const int*)d_in[17];
  float* out = (float*)d_out;

  char* wsb = (char*)d_ws;
  u16* ew1c = (u16*)(wsb + 0);          //  81920 B
  u16* ew2c = (u16*)(wsb + 81920);      //  32768 B
  u16* xw1c = (u16*)(wsb + 114688);     //  32768 B
  u16* nw1c = (u16*)(wsb + 147456);     //  65536 B
  u16* nw2c = (u16*)(wsb + 212992);     //  32768 B
  float* mi = (float*)(wsb + 245760);   // 10240000 B
  float* dx = (float*)(wsb + 10485760); //   240000 B

  hipMemsetAsync(wsb + 245760, 0, 10240000 + 240000, stream);

  prep_kernel<<<(122880 + 255) / 256, 256, 0, stream>>>(
      ew1, ew2, xw1, nw1, nw2, ew1c, ew2c, xw1c, nw1c, nw2c);

  edge_kernel<<<EE / 64, 256, 0, stream>>>(
      h, x, edge_attr, ew1c, eb1, ew2c, eb2, inf_w, inf_b,
      xw1c, xb1, xw2, xb2, edge_index, mi, dx);

  node_kernel<<<(NN + 63) / 64, 256, 0, stream>>>(
      h, x, nw1c, nb1, nw2c, nb2, mi, dx, out);
}